// Round 10
// baseline (73.755 us; speedup 1.0000x reference)
//
#include <hip/hip_runtime.h>
#include <hip/hip_bf16.h>
#include <string.h>

// N=32, C=96, H=W=56. HW=3136, NP=100352.
// d_out = [ out (9,633,792 f32) | fmap (9,633,792 f32) ]
//
// ws layout (float index):
//   [   0, 4608) W1 bf16 A-frags: slot ((g*3+m)*3+k)*64+lane (16 B each),
//                w'[o=16m+(lane&15)][ci=32k+(lane>>4)*8+j], w' = w1*s1
//   [4608, 4800) c1[192] f32: c = b1/s1 (act' = max(x + c, 0))
//   [4800, 6336) W2 bf16 A-frags: slot ((G*2+m))*64+lane,
//                w2[o=G*32+16m+(lane&15)][ci=(lane>>4)*8+j]  (no fold)
//   [6336, 7104) p2[96][8]: s2, b2, w00, w01, w10, w11, ay(int), ax(int)
#define WSC_OFF 4608
#define WS_W2F  4800
#define WS_P    6336

#define HW 3136
#define CC 96
#define NB 32
#define NP 100352
#define LSTR 262   // q-tile px stride: octet bank offsets {0,24,16,8} -> conflict-free

typedef __attribute__((ext_vector_type(8))) short short8;
typedef __attribute__((ext_vector_type(4))) float float4_;

__global__ __launch_bounds__(128) void precompute_k(
    const float* __restrict__ g1, const float* __restrict__ be1,
    const float* __restrict__ m1, const float* __restrict__ v1,
    const float* __restrict__ g2, const float* __restrict__ be2,
    const float* __restrict__ m2, const float* __restrict__ v2,
    const float* __restrict__ w1, const float* __restrict__ w2,
    const float* __restrict__ shift, float* __restrict__ ws) {
  const int t = blockIdx.x * 128 + threadIdx.x;  // 12*128 = 1536 threads
  if (t < 192) {
    float s = g1[t] / sqrtf(v1[t] + 1e-5f);
    float b = be1[t] - m1[t] * s;
    ws[WSC_OFF + t] = b / s;     // gamma > 0 guaranteed
  }
  if (t >= 192 && t < 288) {     // conv2 per-channel params
    int c = t - 192;
    float s = g2[c] / sqrtf(v2[c] + 1e-5f);
    float b = be2[c] - m2[c] * s;
    float dy = shift[2 * c], dx = shift[2 * c + 1];
    float fy = floorf(dy), fx = floorf(dx);
    float wy = dy - fy, wx = dx - fx;
    float* pp = ws + WS_P + c * 8;
    pp[0] = s;
    pp[1] = b;
    pp[2] = (1.f - wy) * (1.f - wx);
    pp[3] = (1.f - wy) * wx;
    pp[4] = wy * (1.f - wx);
    pp[5] = wy * wx;
    pp[6] = __int_as_float((int)fy);
    pp[7] = __int_as_float((int)fx);
  }
  if (t < 1152) {                // W1 fragments (scale-folded bf16)
    const int lane = t & 63;
    const int gmk = t >> 6;      // 0..17
    const int k = gmk % 3;
    const int gm = gmk / 3;
    const int m = gm % 3;
    const int g = gm / 3;
    const int o = 16 * m + (lane & 15);
    const int ci0 = 32 * k + (lane >> 4) * 8;
    unsigned int pk[4];
    for (int jj = 0; jj < 4; ++jj) {
      unsigned short us[2];
      for (int h = 0; h < 2; ++h) {
        int ci = ci0 + 2 * jj + h;
        float s = g1[g * 96 + ci] / sqrtf(v1[g * 96 + ci] + 1e-5f);
        float w = w1[(g * 48 + o) * 96 + ci] * s;
        __hip_bfloat16 hb = __float2bfloat16(w);
        memcpy(&us[h], &hb, 2);
      }
      pk[jj] = (unsigned int)us[0] | ((unsigned int)us[1] << 16);
    }
    uint4 val;
    val.x = pk[0]; val.y = pk[1]; val.z = pk[2]; val.w = pk[3];
    ((uint4*)ws)[t] = val;
  } else if (t < 1536) {         // W2 fragments (plain bf16)
    const int s2i = t - 1152;    // 0..383
    const int lane = s2i & 63;
    const int gm = s2i >> 6;     // 0..5
    const int m = gm & 1;
    const int G = gm >> 1;
    const int o = G * 32 + m * 16 + (lane & 15);
    const int k0 = (lane >> 4) * 8;
    unsigned int pk[4];
    for (int jj = 0; jj < 4; ++jj) {
      unsigned short us[2];
      for (int h = 0; h < 2; ++h) {
        __hip_bfloat16 hb = __float2bfloat16(w2[o * 32 + k0 + 2 * jj + h]);
        memcpy(&us[h], &hb, 2);
      }
      pk[jj] = (unsigned int)us[0] | ((unsigned int)us[1] << 16);
    }
    uint4 val;
    val.x = pk[0]; val.y = pk[1]; val.z = pk[2]; val.w = pk[3];
    ((uint4*)(ws + WS_W2F))[s2i] = val;
  }
}

// ---------------------------------------------------------------------------
// Fused kernel: per block (128 owned px, 8 waves of 512 threads):
//  Phase A: conv1 (MFMA) over the 256-px window [P0-64, P0+192):
//    waves 0-3 -> group 0, waves 4-7 -> group 1; 4 tiles of 16 px each.
//    Writes owned fmap slice (f32, output) + q = relu(bn2(fmap)) bf16 to LDS.
//  Phase B: per owned 16-px tile (wave wv), all 3 conv2-groups:
//    bilinear gather of q from LDS (taps always inside window; invalid taps
//    value-selected to 0), 2 MFMAs per group, + residual, store out.
//  Grid 784 = 8 x 98 XCD-chunk swizzled (halo shared via local XCD L2).
// ---------------------------------------------------------------------------
__global__ __launch_bounds__(512) void fused_k(
    const float* __restrict__ x, const float* __restrict__ prev,
    const float* __restrict__ ws, float* __restrict__ fmap,
    float* __restrict__ out) {
  __shared__ unsigned short qlds[CC * LSTR];   // 50,304 B

  const int tid = threadIdx.x;
  const int lane = tid & 63;
  const int wv = tid >> 6;       // 0..7
  const int qq = lane >> 4;      // 0..3
  const int colL = lane & 15;
  const int blk = (blockIdx.x & 7) * 98 + (blockIdx.x >> 3);  // 784 = 8*98
  const int P0 = blk * 128;      // owned [P0, P0+128)

  // ---------------- Phase A ----------------
  {
    const int g = wv >> 2;
    short8 A[3][3];
    const short8* wf = (const short8*)ws;
#pragma unroll
    for (int m = 0; m < 3; ++m)
#pragma unroll
      for (int k = 0; k < 3; ++k)
        A[m][k] = wf[((g * 3 + m) * 3 + k) * 64 + lane];

    float c_[3][8];
#pragma unroll
    for (int k = 0; k < 3; ++k) {
      const float* cp = ws + WSC_OFF + g * 96 + 32 * k + 8 * qq;
#pragma unroll
      for (int j = 0; j < 8; ++j) c_[k][j] = cp[j];
    }
    float s2r[3][4], b2r[3][4];
#pragma unroll
    for (int m = 0; m < 3; ++m)
#pragma unroll
      for (int r = 0; r < 4; ++r) {
        const int ch = 48 * g + 16 * m + 4 * qq + r;
        const float* pp = ws + WS_P + ch * 8;
        s2r[m][r] = pp[0];
        b2r[m][r] = pp[1];
      }

#pragma unroll
    for (int t = 0; t < 4; ++t) {
      const int lt = (wv & 3) * 4 + t;       // window tile 0..15
      const int Pt = P0 - 64 + lt * 16;
      const int lpx = lt * 16 + colL;
      if ((unsigned)Pt >= (unsigned)NP) {    // whole tile outside tensor
#pragma unroll
        for (int m = 0; m < 3; ++m)
#pragma unroll
          for (int r = 0; r < 4; ++r)
            qlds[(48 * g + 16 * m + 4 * qq + r) * LSTR + lpx] = 0;
        continue;
      }
      const int P = Pt + colL;
      const int n = P / HW;
      const int p = P - n * HW;
      const size_t nb = (size_t)n * CC * HW;

      float4_ D[3] = {{0.f,0.f,0.f,0.f},{0.f,0.f,0.f,0.f},{0.f,0.f,0.f,0.f}};
#pragma unroll
      for (int k = 0; k < 3; ++k) {
        const int ci0 = 32 * k + 8 * qq;     // octets never straddle the split
        const float* src = (ci0 < 48)
            ? (x + nb + (size_t)(g * 48 + ci0) * HW + p)
            : (prev + nb + (size_t)((1 - g) * 48 + (ci0 - 48)) * HW + p);
        short8 B;
#pragma unroll
        for (int j = 0; j < 8; ++j) {
          float f = fmaxf(src[(size_t)j * HW] + c_[k][j], 0.f);
          __hip_bfloat16 hb = __float2bfloat16(f);
          unsigned short us; memcpy(&us, &hb, 2);
          B[j] = (short)us;
        }
#pragma unroll
        for (int m = 0; m < 3; ++m)
          D[m] = __builtin_amdgcn_mfma_f32_16x16x32_bf16(A[m][k], B, D[m],
                                                         0, 0, 0);
      }
      if (lt >= 4 && lt < 12) {              // owned px: write fmap output
        float* fb = fmap + nb + (size_t)(g * 48) * HW + p;
#pragma unroll
        for (int m = 0; m < 3; ++m)
#pragma unroll
          for (int r = 0; r < 4; ++r)
            fb[(size_t)(16 * m + 4 * qq + r) * HW] = D[m][r];
      }
#pragma unroll
      for (int m = 0; m < 3; ++m)
#pragma unroll
        for (int r = 0; r < 4; ++r) {
          float qv = fmaxf(fmaf(D[m][r], s2r[m][r], b2r[m][r]), 0.f);
          __hip_bfloat16 hb = __float2bfloat16(qv);
          unsigned short us; memcpy(&us, &hb, 2);
          qlds[(48 * g + 16 * m + 4 * qq + r) * LSTR + lpx] = us;
        }
    }
  }
  __syncthreads();

  // ---------------- Phase B ----------------
  {
    const int Lpx = 64 + wv * 16 + colL;     // window-local px
    const int P = P0 + wv * 16 + colL;
    const int n = P / HW;
    const int p = P - n * HW;
    const int y = p / 56;
    const int xx = p - y * 56;
    const short8* wf2 = (const short8*)(ws + WS_W2F);

#pragma unroll
    for (int G = 0; G < 3; ++G) {
      short8 A0 = wf2[(G * 2 + 0) * 64 + lane];
      short8 A1 = wf2[(G * 2 + 1) * 64 + lane];
      short8 B;
#pragma unroll
      for (int j = 0; j < 8; ++j) {
        const int ch = G * 32 + 8 * qq + j;
        const float* pp = ws + WS_P + ch * 8;
        const float w00 = pp[2], w01 = pp[3], w10 = pp[4], w11 = pp[5];
        const int ay = __float_as_int(pp[6]);
        const int ax = __float_as_int(pp[7]);
        // tap base in window coords: Lpx+off in [7,191]; +57 <= 248 < LSTR
        const unsigned short* qc = qlds + ch * LSTR + (Lpx + ay * 56 + ax);
        const int yq = y + ay, xq = xx + ax;
        const bool vy0 = yq >= 0, vy1 = yq <= 54;
        const bool vx0 = xq >= 0, vx1 = xq <= 54;
        float f00 = (vy0 && vx0) ? __uint_as_float((unsigned)qc[0] << 16) : 0.f;
        float f01 = (vy0 && vx1) ? __uint_as_float((unsigned)qc[1] << 16) : 0.f;
        float f10 = (vy1 && vx0) ? __uint_as_float((unsigned)qc[56] << 16) : 0.f;
        float f11 = (vy1 && vx1) ? __uint_as_float((unsigned)qc[57] << 16) : 0.f;
        float h = w00 * f00;
        h = fmaf(w01, f01, h);
        h = fmaf(w10, f10, h);
        h = fmaf(w11, f11, h);
        __hip_bfloat16 hb = __float2bfloat16(h);
        unsigned short us; memcpy(&us, &hb, 2);
        B[j] = (short)us;
      }
      const int cb = n * CC + G * 32;
      const float* xb = x + (size_t)cb * HW + p;
      float* ob = out + (size_t)cb * HW + p;
      float4_ D0 = {0.f,0.f,0.f,0.f};
      float4_ D1 = {0.f,0.f,0.f,0.f};
      D0 = __builtin_amdgcn_mfma_f32_16x16x32_bf16(A0, B, D0, 0, 0, 0);
      D1 = __builtin_amdgcn_mfma_f32_16x16x32_bf16(A1, B, D1, 0, 0, 0);
#pragma unroll
      for (int r = 0; r < 4; ++r) {
        ob[(size_t)(qq * 4 + r) * HW] = D0[r] + xb[(size_t)(qq * 4 + r) * HW];
        ob[(size_t)(16 + qq * 4 + r) * HW] =
            D1[r] + xb[(size_t)(16 + qq * 4 + r) * HW];
      }
    }
  }
}

extern "C" void kernel_launch(void* const* d_in, const int* in_sizes, int n_in,
                              void* d_out, int out_size, void* d_ws, size_t ws_size,
                              hipStream_t stream) {
  const float* x     = (const float*)d_in[0];
  const float* prev  = (const float*)d_in[1];
  const float* g1    = (const float*)d_in[2];
  const float* be1   = (const float*)d_in[3];
  const float* m1    = (const float*)d_in[4];
  const float* v1    = (const float*)d_in[5];
  const float* g2    = (const float*)d_in[6];
  const float* be2   = (const float*)d_in[7];
  const float* m2    = (const float*)d_in[8];
  const float* v2    = (const float*)d_in[9];
  const float* w1    = (const float*)d_in[10];
  const float* w2    = (const float*)d_in[11];
  const float* shift = (const float*)d_in[12];

  float* out  = (float*)d_out;
  float* fmap = out + (size_t)NB * CC * HW;  // second output, written in place
  float* ws   = (float*)d_ws;

  precompute_k<<<12, 128, 0, stream>>>(g1, be1, m1, v1, g2, be2, m2, v2,
                                       w1, w2, shift, ws);
  fused_k<<<784, 512, 0, stream>>>(x, prev, ws, fmap, out);
}

// Round 11
// 61.624 us; speedup vs baseline: 1.1969x; 1.1969x over previous
//
#include <hip/hip_runtime.h>
#include <hip/hip_bf16.h>
#include <string.h>

// N=32, C=96, H=W=56. HW=3136, NP=100352.
// d_out = [ out (9,633,792 f32) | fmap (9,633,792 f32) ]
//
// ws layout (float index):
//   [   0, 4608) W1 bf16 A-frags: slot ((g*3+m)*3+k)*64+lane (16 B each),
//                w'[o=16m+(lane&15)][ci=32k+(lane>>4)*8+j], w' = w1*s1
//   [4608, 4800) c1[192] f32: c = b1/s1 (act' = max(x + c, 0))
//   [4800, 6336) W2 bf16 A-frags: slot ((G*2+m))*64+lane,
//                w2[o=G*32+16m+(lane&15)][ci=(lane>>4)*8+j]  (no fold)
//   [6336, 7104) p2[96][8]: c2=b2/s2, w00*s2, w01*s2, w10*s2, w11*s2,
//                ayax packed, off = ay*56+ax, pad
#define WSC_OFF 4608
#define WS_W2F  4800
#define WS_P    6336

#define HW 3136
#define CC 96
#define NB 32

typedef __attribute__((ext_vector_type(8))) short short8;
typedef __attribute__((ext_vector_type(4))) float float4_;

__global__ __launch_bounds__(128) void precompute_k(
    const float* __restrict__ g1, const float* __restrict__ be1,
    const float* __restrict__ m1, const float* __restrict__ v1,
    const float* __restrict__ g2, const float* __restrict__ be2,
    const float* __restrict__ m2, const float* __restrict__ v2,
    const float* __restrict__ w1, const float* __restrict__ w2,
    const float* __restrict__ shift, float* __restrict__ ws) {
  const int t = blockIdx.x * 128 + threadIdx.x;  // 12*128 = 1536 threads
  if (t < 192) {
    float s = g1[t] / sqrtf(v1[t] + 1e-5f);
    float b = be1[t] - m1[t] * s;
    ws[WSC_OFF + t] = b / s;     // gamma > 0 guaranteed
  }
  if (t >= 192 && t < 288) {     // conv2 per-channel params (s2 folded into w)
    int c = t - 192;
    float s = g2[c] / sqrtf(v2[c] + 1e-5f);
    float b = be2[c] - m2[c] * s;
    float dy = shift[2 * c], dx = shift[2 * c + 1];
    float fy = floorf(dy), fx = floorf(dx);
    float wy = dy - fy, wx = dx - fx;
    int ay = (int)fy, ax = (int)fx;
    float* pp = ws + WS_P + c * 8;
    pp[0] = b / s;                       // c2: q = s*relu(f + c2)
    pp[1] = (1.f - wy) * (1.f - wx) * s;
    pp[2] = (1.f - wy) * wx * s;
    pp[3] = wy * (1.f - wx) * s;
    pp[4] = wy * wx * s;
    pp[5] = __int_as_float((ay << 16) | (ax & 0xffff));
    pp[6] = __int_as_float(ay * 56 + ax);
    pp[7] = 0.f;
  }
  if (t < 1152) {                // W1 fragments (scale-folded bf16)
    const int lane = t & 63;
    const int gmk = t >> 6;      // 0..17
    const int k = gmk % 3;
    const int gm = gmk / 3;
    const int m = gm % 3;
    const int g = gm / 3;
    const int o = 16 * m + (lane & 15);
    const int ci0 = 32 * k + (lane >> 4) * 8;
    unsigned int pk[4];
    for (int jj = 0; jj < 4; ++jj) {
      unsigned short us[2];
      for (int h = 0; h < 2; ++h) {
        int ci = ci0 + 2 * jj + h;
        float s = g1[g * 96 + ci] / sqrtf(v1[g * 96 + ci] + 1e-5f);
        float w = w1[(g * 48 + o) * 96 + ci] * s;
        __hip_bfloat16 hb = __float2bfloat16(w);
        memcpy(&us[h], &hb, 2);
      }
      pk[jj] = (unsigned int)us[0] | ((unsigned int)us[1] << 16);
    }
    uint4 val;
    val.x = pk[0]; val.y = pk[1]; val.z = pk[2]; val.w = pk[3];
    ((uint4*)ws)[t] = val;
  } else if (t < 1536) {         // W2 fragments (plain bf16)
    const int s2i = t - 1152;    // 0..383
    const int lane = s2i & 63;
    const int gm = s2i >> 6;     // 0..5
    const int m = gm & 1;
    const int G = gm >> 1;
    const int o = G * 32 + m * 16 + (lane & 15);
    const int k0 = (lane >> 4) * 8;
    unsigned int pk[4];
    for (int jj = 0; jj < 4; ++jj) {
      unsigned short us[2];
      for (int h = 0; h < 2; ++h) {
        __hip_bfloat16 hb = __float2bfloat16(w2[o * 32 + k0 + 2 * jj + h]);
        memcpy(&us[h], &hb, 2);
      }
      pk[jj] = (unsigned int)us[0] | ((unsigned int)us[1] << 16);
    }
    uint4 val;
    val.x = pk[0]; val.y = pk[1]; val.z = pk[2]; val.w = pk[3];
    ((uint4*)(ws + WS_W2F))[s2i] = val;
  }
}

// ---------------------------------------------------------------------------
// K1 (MFMA): fmap = conv1x1_g2( bnrelu1( concat ), w1 )
// grid (392, 2): x = 256-px strip (XCD-chunk swizzled, 49/XCD), y = group.
// Block 512 = 8 waves; wave = 2 tiles of 16 px (32 px). 6272 waves total
// (24.5/CU) — doubled vs round 9 for latency hiding.
// ---------------------------------------------------------------------------
__global__ __launch_bounds__(512) void k1_conv1(
    const float* __restrict__ x, const float* __restrict__ prev,
    const float* __restrict__ ws, float* __restrict__ fmap) {
  const int tid = threadIdx.x;
  const int lane = tid & 63;
  const int wv = tid >> 6;       // 0..7
  const int g = blockIdx.y;
  const int strip = (blockIdx.x & 7) * 49 + (blockIdx.x >> 3);  // 392 = 8*49
  const int q = lane >> 4;       // 0..3
  const int colL = lane & 15;

  short8 A[3][3];
  const short8* wf = (const short8*)ws;
#pragma unroll
  for (int m = 0; m < 3; ++m)
#pragma unroll
    for (int k = 0; k < 3; ++k)
      A[m][k] = wf[((g * 3 + m) * 3 + k) * 64 + lane];

  float c_[3][8];
#pragma unroll
  for (int k = 0; k < 3; ++k) {
    const float* cp = ws + WSC_OFF + g * 96 + 32 * k + 8 * q;
#pragma unroll
    for (int j = 0; j < 8; ++j) c_[k][j] = cp[j];
  }

  const int Pw = strip * 256 + wv * 32;   // 32 | 3136: n const per wave
  const int n = Pw / HW;
  const int pw = Pw - n * HW;
  const size_t nb = (size_t)n * CC * HW;

  // per-k source base (octets never straddle the x/prev split)
  const float* sb[3];
#pragma unroll
  for (int k = 0; k < 3; ++k) {
    const int ci0 = 32 * k + 8 * q;
    sb[k] = (ci0 < 48)
        ? (x + nb + (size_t)(g * 48 + ci0) * HW)
        : (prev + nb + (size_t)((1 - g) * 48 + (ci0 - 48)) * HW);
  }
  float* fb = fmap + nb + (size_t)(g * 48) * HW;

#pragma unroll
  for (int t = 0; t < 2; ++t) {
    const int col = pw + t * 16 + colL;
    float4_ D[3] = {{0.f, 0.f, 0.f, 0.f}, {0.f, 0.f, 0.f, 0.f},
                    {0.f, 0.f, 0.f, 0.f}};
#pragma unroll
    for (int k = 0; k < 3; ++k) {
      float a[8];
#pragma unroll
      for (int j = 0; j < 8; ++j) a[j] = sb[k][(size_t)j * HW + col];
      short8 B;
#pragma unroll
      for (int j = 0; j < 8; ++j) {
        float f = fmaxf(a[j] + c_[k][j], 0.f);
        __hip_bfloat16 hb = __float2bfloat16(f);
        unsigned short us;
        memcpy(&us, &hb, 2);
        B[j] = (short)us;
      }
#pragma unroll
      for (int m = 0; m < 3; ++m)
        D[m] = __builtin_amdgcn_mfma_f32_16x16x32_bf16(A[m][k], B, D[m],
                                                       0, 0, 0);
    }
#pragma unroll
    for (int m = 0; m < 3; ++m)
#pragma unroll
      for (int r = 0; r < 4; ++r)
        fb[(size_t)(16 * m + q * 4 + r) * HW + col] = D[m][r];
  }
}

// ---------------------------------------------------------------------------
// K2 (MFMA): out = conv1x1_g3( active_shift( bnrelu2(fmap) ), w2 ) + x
// grid (392, 3): x = 256-px strip (same swizzle), y = group.
// Block 512 = 8 waves; wave = 2 tiles of 16 px. 9408 waves (36.7/CU).
// s2 folded into tap weights: h = sum w_tap*s2*relu(f_tap + c2).
// ---------------------------------------------------------------------------
__global__ __launch_bounds__(512) void k2_shift_conv2(
    const float* __restrict__ x, const float* __restrict__ fmap,
    const float* __restrict__ ws, float* __restrict__ out) {
  const int tid = threadIdx.x;
  const int G = blockIdx.y;        // group 0..2
  const int lane = tid & 63;
  const int wv = tid >> 6;         // 0..7
  const int q = lane >> 4;
  const int colL = lane & 15;
  const int strip = (blockIdx.x & 7) * 49 + (blockIdx.x >> 3);  // 392 = 8*49

  short8 A0, A1;
  {
    const short8* wf2 = (const short8*)(ws + WS_W2F);
    A0 = wf2[(G * 2 + 0) * 64 + lane];
    A1 = wf2[(G * 2 + 1) * 64 + lane];
  }

  float c2_[8], w00_[8], w01_[8], w10_[8], w11_[8];
  int off_[8], ay_[8], ax_[8];
#pragma unroll
  for (int j = 0; j < 8; ++j) {
    const float* pp = ws + WS_P + (G * 32 + q * 8 + j) * 8;
    c2_[j] = pp[0];
    w00_[j] = pp[1];
    w01_[j] = pp[2];
    w10_[j] = pp[3];
    w11_[j] = pp[4];
    const int ayax = __float_as_int(pp[5]);
    ay_[j] = ayax >> 16;
    ax_[j] = (short)(ayax & 0xffff);
    off_[j] = __float_as_int(pp[6]);
  }

  const int Pw = strip * 256 + wv * 32;   // 32 | 3136: n const per wave
  const int n = Pw / HW;
  const int pw = Pw - n * HW;
  const int cb = n * CC + G * 32;
  const float* fb = fmap + (size_t)cb * HW;
  const float* xb = x + (size_t)cb * HW;
  float* ob = out + (size_t)cb * HW;

#pragma unroll
  for (int t = 0; t < 2; ++t) {
    const int p = pw + t * 16 + colL;
    const int y = p / 56;
    const int xx = p - y * 56;

    // residual prefetch (independent of gather chain)
    float xr0[4], xr1[4];
#pragma unroll
    for (int r = 0; r < 4; ++r) {
      xr0[r] = xb[(size_t)(q * 4 + r) * HW + p];
      xr1[r] = xb[(size_t)(16 + q * 4 + r) * HW + p];
    }

    short8 B;
#pragma unroll
    for (int j = 0; j < 8; ++j) {
      const int ci = q * 8 + j;
      const float* fc = fb + (size_t)ci * HW;
      const int to = p + off_[j];
      float f00 = fc[to];
      float f01 = fc[min(to + 1, HW - 1)];
      float f10 = fc[min(to + 56, HW - 1)];
      float f11 = fc[min(to + 57, HW - 1)];
      float q00 = fmaxf(f00 + c2_[j], 0.f);
      float q01 = fmaxf(f01 + c2_[j], 0.f);
      float q10 = fmaxf(f10 + c2_[j], 0.f);
      float q11 = fmaxf(f11 + c2_[j], 0.f);
      const int yq = y + ay_[j], xq = xx + ax_[j];
      const bool vy0 = yq >= 0, vy1 = yq <= 54;
      const bool vx0 = xq >= 0, vx1 = xq <= 54;
      float h = ((vy0 && vx0) ? w00_[j] : 0.f) * q00;
      h = fmaf(((vy0 && vx1) ? w01_[j] : 0.f), q01, h);
      h = fmaf(((vy1 && vx0) ? w10_[j] : 0.f), q10, h);
      h = fmaf(((vy1 && vx1) ? w11_[j] : 0.f), q11, h);
      __hip_bfloat16 hb = __float2bfloat16(h);
      unsigned short us;
      memcpy(&us, &hb, 2);
      B[j] = (short)us;
    }

    float4_ D0 = {0.f, 0.f, 0.f, 0.f};
    float4_ D1 = {0.f, 0.f, 0.f, 0.f};
    D0 = __builtin_amdgcn_mfma_f32_16x16x32_bf16(A0, B, D0, 0, 0, 0);
    D1 = __builtin_amdgcn_mfma_f32_16x16x32_bf16(A1, B, D1, 0, 0, 0);

#pragma unroll
    for (int r = 0; r < 4; ++r) {
      ob[(size_t)(q * 4 + r) * HW + p] = D0[r] + xr0[r];
      ob[(size_t)(16 + q * 4 + r) * HW + p] = D1[r] + xr1[r];
    }
  }
}

extern "C" void kernel_launch(void* const* d_in, const int* in_sizes, int n_in,
                              void* d_out, int out_size, void* d_ws, size_t ws_size,
                              hipStream_t stream) {
  const float* x     = (const float*)d_in[0];
  const float* prev  = (const float*)d_in[1];
  const float* g1    = (const float*)d_in[2];
  const float* be1   = (const float*)d_in[3];
  const float* m1    = (const float*)d_in[4];
  const float* v1    = (const float*)d_in[5];
  const float* g2    = (const float*)d_in[6];
  const float* be2   = (const float*)d_in[7];
  const float* m2    = (const float*)d_in[8];
  const float* v2    = (const float*)d_in[9];
  const float* w1    = (const float*)d_in[10];
  const float* w2    = (const float*)d_in[11];
  const float* shift = (const float*)d_in[12];

  float* out  = (float*)d_out;
  float* fmap = out + (size_t)NB * CC * HW;  // second output, written in place
  float* ws   = (float*)d_ws;

  precompute_k<<<12, 128, 0, stream>>>(g1, be1, m1, v1, g2, be2, m2, v2,
                                       w1, w2, shift, ws);
  k1_conv1<<<dim3(392, 2), 512, 0, stream>>>(x, prev, ws, fmap);
  k2_shift_conv2<<<dim3(392, 3), 512, 0, stream>>>(x, fmap, ws, out);
}

// Round 12
// 59.457 us; speedup vs baseline: 1.2405x; 1.0364x over previous
//
#include <hip/hip_runtime.h>
#include <hip/hip_bf16.h>
#include <string.h>

// N=32, C=96, H=W=56. HW=3136, NP=100352.
// d_out = [ out (9,633,792 f32) | fmap (9,633,792 f32) ]
//
// ws layout (float index):
//   [   0, 4608) W1 bf16 A-frags: slot ((g*3+m)*3+k)*64+lane (16 B each),
//                w'[o=16m+(lane&15)][ci=32k+(lane>>4)*8+j], w' = w1*s1
//   [4608, 4800) c1[192] f32: c = b1/s1 (act' = max(x + c, 0))
//   [4800, 6336) W2 bf16 A-frags: slot ((G*2+m))*64+lane,
//                w2[o=G*32+16m+(lane&15)][ci=(lane>>4)*8+j]  (no fold)
//   [6336, 7104) p2[96][8]: c2=b2/s2, w00*s2, w01*s2, w10*s2, w11*s2,
//                ayax packed, off = ay*56+ax, pad
#define WSC_OFF 4608
#define WS_W2F  4800
#define WS_P    6336

#define HW 3136
#define CC 96
#define NB 32

typedef __attribute__((ext_vector_type(8))) short short8;
typedef __attribute__((ext_vector_type(4))) float float4_;

__global__ __launch_bounds__(128) void precompute_k(
    const float* __restrict__ g1, const float* __restrict__ be1,
    const float* __restrict__ m1, const float* __restrict__ v1,
    const float* __restrict__ g2, const float* __restrict__ be2,
    const float* __restrict__ m2, const float* __restrict__ v2,
    const float* __restrict__ w1, const float* __restrict__ w2,
    const float* __restrict__ shift, float* __restrict__ ws) {
  const int t = blockIdx.x * 128 + threadIdx.x;  // 12*128 = 1536 threads
  if (t < 192) {
    float s = g1[t] / sqrtf(v1[t] + 1e-5f);
    float b = be1[t] - m1[t] * s;
    ws[WSC_OFF + t] = b / s;     // gamma > 0 guaranteed
  }
  if (t >= 192 && t < 288) {     // conv2 per-channel params (s2 folded into w)
    int c = t - 192;
    float s = g2[c] / sqrtf(v2[c] + 1e-5f);
    float b = be2[c] - m2[c] * s;
    float dy = shift[2 * c], dx = shift[2 * c + 1];
    float fy = floorf(dy), fx = floorf(dx);
    float wy = dy - fy, wx = dx - fx;
    int ay = (int)fy, ax = (int)fx;
    float* pp = ws + WS_P + c * 8;
    pp[0] = b / s;                       // c2: q = s*relu(f + c2)
    pp[1] = (1.f - wy) * (1.f - wx) * s;
    pp[2] = (1.f - wy) * wx * s;
    pp[3] = wy * (1.f - wx) * s;
    pp[4] = wy * wx * s;
    pp[5] = __int_as_float((ay << 16) | (ax & 0xffff));
    pp[6] = __int_as_float(ay * 56 + ax);
    pp[7] = 0.f;
  }
  if (t < 1152) {                // W1 fragments (scale-folded bf16)
    const int lane = t & 63;
    const int gmk = t >> 6;      // 0..17
    const int k = gmk % 3;
    const int gm = gmk / 3;
    const int m = gm % 3;
    const int g = gm / 3;
    const int o = 16 * m + (lane & 15);
    const int ci0 = 32 * k + (lane >> 4) * 8;
    unsigned int pk[4];
    for (int jj = 0; jj < 4; ++jj) {
      unsigned short us[2];
      for (int h = 0; h < 2; ++h) {
        int ci = ci0 + 2 * jj + h;
        float s = g1[g * 96 + ci] / sqrtf(v1[g * 96 + ci] + 1e-5f);
        float w = w1[(g * 48 + o) * 96 + ci] * s;
        __hip_bfloat16 hb = __float2bfloat16(w);
        memcpy(&us[h], &hb, 2);
      }
      pk[jj] = (unsigned int)us[0] | ((unsigned int)us[1] << 16);
    }
    uint4 val;
    val.x = pk[0]; val.y = pk[1]; val.z = pk[2]; val.w = pk[3];
    ((uint4*)ws)[t] = val;
  } else if (t < 1536) {         // W2 fragments (plain bf16)
    const int s2i = t - 1152;    // 0..383
    const int lane = s2i & 63;
    const int gm = s2i >> 6;     // 0..5
    const int m = gm & 1;
    const int G = gm >> 1;
    const int o = G * 32 + m * 16 + (lane & 15);
    const int k0 = (lane >> 4) * 8;
    unsigned int pk[4];
    for (int jj = 0; jj < 4; ++jj) {
      unsigned short us[2];
      for (int h = 0; h < 2; ++h) {
        __hip_bfloat16 hb = __float2bfloat16(w2[o * 32 + k0 + 2 * jj + h]);
        memcpy(&us[h], &hb, 2);
      }
      pk[jj] = (unsigned int)us[0] | ((unsigned int)us[1] << 16);
    }
    uint4 val;
    val.x = pk[0]; val.y = pk[1]; val.z = pk[2]; val.w = pk[3];
    ((uint4*)(ws + WS_W2F))[s2i] = val;
  }
}

// ---------------------------------------------------------------------------
// K1 (MFMA): fmap = conv1x1_g2( bnrelu1( concat ), w1 )
// grid (784, 2): x = 128-px strip, y = group. Block 256 = 4 waves;
// wave = 2 tiles of 16 px (32 px). 6272 waves (24.5/CU) in 1568 fine-grained
// blocks — round-5's proven dispatch shape (512-thr blocks cost +13 us, r11).
// Swizzle: strip b -> XCD b/98, aligned with K2 (px/12544 on both sides).
// ---------------------------------------------------------------------------
__global__ __launch_bounds__(256) void k1_conv1(
    const float* __restrict__ x, const float* __restrict__ prev,
    const float* __restrict__ ws, float* __restrict__ fmap) {
  const int tid = threadIdx.x;
  const int lane = tid & 63;
  const int wv = tid >> 6;       // 0..3
  const int g = blockIdx.y;
  const int strip = (blockIdx.x & 7) * 98 + (blockIdx.x >> 3);  // 784 = 8*98
  const int q = lane >> 4;       // 0..3
  const int colL = lane & 15;

  short8 A[3][3];
  const short8* wf = (const short8*)ws;
#pragma unroll
  for (int m = 0; m < 3; ++m)
#pragma unroll
    for (int k = 0; k < 3; ++k)
      A[m][k] = wf[((g * 3 + m) * 3 + k) * 64 + lane];

  float c_[3][8];
#pragma unroll
  for (int k = 0; k < 3; ++k) {
    const float* cp = ws + WSC_OFF + g * 96 + 32 * k + 8 * q;
#pragma unroll
    for (int j = 0; j < 8; ++j) c_[k][j] = cp[j];
  }

  const int Pw = strip * 128 + wv * 32;   // 32 | 3136: n const per wave
  const int n = Pw / HW;
  const int pw = Pw - n * HW;
  const size_t nb = (size_t)n * CC * HW;

  // per-k source base (octets never straddle the x/prev split)
  const float* sb[3];
#pragma unroll
  for (int k = 0; k < 3; ++k) {
    const int ci0 = 32 * k + 8 * q;
    sb[k] = (ci0 < 48)
        ? (x + nb + (size_t)(g * 48 + ci0) * HW)
        : (prev + nb + (size_t)((1 - g) * 48 + (ci0 - 48)) * HW);
  }
  float* fb = fmap + nb + (size_t)(g * 48) * HW;

#pragma unroll
  for (int t = 0; t < 2; ++t) {
    const int col = pw + t * 16 + colL;
    float4_ D[3] = {{0.f, 0.f, 0.f, 0.f}, {0.f, 0.f, 0.f, 0.f},
                    {0.f, 0.f, 0.f, 0.f}};
#pragma unroll
    for (int k = 0; k < 3; ++k) {
      float a[8];
#pragma unroll
      for (int j = 0; j < 8; ++j) a[j] = sb[k][(size_t)j * HW + col];
      short8 B;
#pragma unroll
      for (int j = 0; j < 8; ++j) {
        float f = fmaxf(a[j] + c_[k][j], 0.f);
        __hip_bfloat16 hb = __float2bfloat16(f);
        unsigned short us;
        memcpy(&us, &hb, 2);
        B[j] = (short)us;
      }
#pragma unroll
      for (int m = 0; m < 3; ++m)
        D[m] = __builtin_amdgcn_mfma_f32_16x16x32_bf16(A[m][k], B, D[m],
                                                       0, 0, 0);
    }
#pragma unroll
    for (int m = 0; m < 3; ++m)
#pragma unroll
      for (int r = 0; r < 4; ++r)
        fb[(size_t)(16 * m + q * 4 + r) * HW + col] = D[m][r];
  }
}

// ---------------------------------------------------------------------------
// K2 (MFMA): out = conv1x1_g3( active_shift( bnrelu2(fmap) ), w2 ) + x
// grid (392, 3): x = 256-px strip (XCD-chunk swizzled), y = group.
// Block 512 = 8 waves; wave = 2 tiles of 16 px. 9408 waves (full occupancy).
// s2 folded into tap weights. (Round-11 version, measured ~14 us.)
// ---------------------------------------------------------------------------
__global__ __launch_bounds__(512) void k2_shift_conv2(
    const float* __restrict__ x, const float* __restrict__ fmap,
    const float* __restrict__ ws, float* __restrict__ out) {
  const int tid = threadIdx.x;
  const int G = blockIdx.y;        // group 0..2
  const int lane = tid & 63;
  const int wv = tid >> 6;         // 0..7
  const int q = lane >> 4;
  const int colL = lane & 15;
  const int strip = (blockIdx.x & 7) * 49 + (blockIdx.x >> 3);  // 392 = 8*49

  short8 A0, A1;
  {
    const short8* wf2 = (const short8*)(ws + WS_W2F);
    A0 = wf2[(G * 2 + 0) * 64 + lane];
    A1 = wf2[(G * 2 + 1) * 64 + lane];
  }

  float c2_[8], w00_[8], w01_[8], w10_[8], w11_[8];
  int off_[8], ay_[8], ax_[8];
#pragma unroll
  for (int j = 0; j < 8; ++j) {
    const float* pp = ws + WS_P + (G * 32 + q * 8 + j) * 8;
    c2_[j] = pp[0];
    w00_[j] = pp[1];
    w01_[j] = pp[2];
    w10_[j] = pp[3];
    w11_[j] = pp[4];
    const int ayax = __float_as_int(pp[5]);
    ay_[j] = ayax >> 16;
    ax_[j] = (short)(ayax & 0xffff);
    off_[j] = __float_as_int(pp[6]);
  }

  const int Pw = strip * 256 + wv * 32;   // 32 | 3136: n const per wave
  const int n = Pw / HW;
  const int pw = Pw - n * HW;
  const int cb = n * CC + G * 32;
  const float* fb = fmap + (size_t)cb * HW;
  const float* xb = x + (size_t)cb * HW;
  float* ob = out + (size_t)cb * HW;

#pragma unroll
  for (int t = 0; t < 2; ++t) {
    const int p = pw + t * 16 + colL;
    const int y = p / 56;
    const int xx = p - y * 56;

    // residual prefetch (independent of gather chain)
    float xr0[4], xr1[4];
#pragma unroll
    for (int r = 0; r < 4; ++r) {
      xr0[r] = xb[(size_t)(q * 4 + r) * HW + p];
      xr1[r] = xb[(size_t)(16 + q * 4 + r) * HW + p];
    }

    short8 B;
#pragma unroll
    for (int j = 0; j < 8; ++j) {
      const int ci = q * 8 + j;
      const float* fc = fb + (size_t)ci * HW;
      const int to = p + off_[j];
      float f00 = fc[to];
      float f01 = fc[min(to + 1, HW - 1)];
      float f10 = fc[min(to + 56, HW - 1)];
      float f11 = fc[min(to + 57, HW - 1)];
      float q00 = fmaxf(f00 + c2_[j], 0.f);
      float q01 = fmaxf(f01 + c2_[j], 0.f);
      float q10 = fmaxf(f10 + c2_[j], 0.f);
      float q11 = fmaxf(f11 + c2_[j], 0.f);
      const int yq = y + ay_[j], xq = xx + ax_[j];
      const bool vy0 = yq >= 0, vy1 = yq <= 54;
      const bool vx0 = xq >= 0, vx1 = xq <= 54;
      float h = ((vy0 && vx0) ? w00_[j] : 0.f) * q00;
      h = fmaf(((vy0 && vx1) ? w01_[j] : 0.f), q01, h);
      h = fmaf(((vy1 && vx0) ? w10_[j] : 0.f), q10, h);
      h = fmaf(((vy1 && vx1) ? w11_[j] : 0.f), q11, h);
      __hip_bfloat16 hb = __float2bfloat16(h);
      unsigned short us;
      memcpy(&us, &hb, 2);
      B[j] = (short)us;
    }

    float4_ D0 = {0.f, 0.f, 0.f, 0.f};
    float4_ D1 = {0.f, 0.f, 0.f, 0.f};
    D0 = __builtin_amdgcn_mfma_f32_16x16x32_bf16(A0, B, D0, 0, 0, 0);
    D1 = __builtin_amdgcn_mfma_f32_16x16x32_bf16(A1, B, D1, 0, 0, 0);

#pragma unroll
    for (int r = 0; r < 4; ++r) {
      ob[(size_t)(q * 4 + r) * HW + p] = D0[r] + xr0[r];
      ob[(size_t)(16 + q * 4 + r) * HW + p] = D1[r] + xr1[r];
    }
  }
}

extern "C" void kernel_launch(void* const* d_in, const int* in_sizes, int n_in,
                              void* d_out, int out_size, void* d_ws, size_t ws_size,
                              hipStream_t stream) {
  const float* x     = (const float*)d_in[0];
  const float* prev  = (const float*)d_in[1];
  const float* g1    = (const float*)d_in[2];
  const float* be1   = (const float*)d_in[3];
  const float* m1    = (const float*)d_in[4];
  const float* v1    = (const float*)d_in[5];
  const float* g2    = (const float*)d_in[6];
  const float* be2   = (const float*)d_in[7];
  const float* m2    = (const float*)d_in[8];
  const float* v2    = (const float*)d_in[9];
  const float* w1    = (const float*)d_in[10];
  const float* w2    = (const float*)d_in[11];
  const float* shift = (const float*)d_in[12];

  float* out  = (float*)d_out;
  float* fmap = out + (size_t)NB * CC * HW;  // second output, written in place
  float* ws   = (float*)d_ws;

  precompute_k<<<12, 128, 0, stream>>>(g1, be1, m1, v1, g2, be2, m2, v2,
                                       w1, w2, shift, ws);
  k1_conv1<<<dim3(784, 2), 256, 0, stream>>>(x, prev, ws, fmap);
  k2_shift_conv2<<<dim3(392, 3), 512, 0, stream>>>(x, fmap, ws, out);
}

// Round 13
// 58.150 us; speedup vs baseline: 1.2684x; 1.0225x over previous
//
#include <hip/hip_runtime.h>
#include <hip/hip_bf16.h>
#include <string.h>

// N=32, C=96, H=W=56. HW=3136, NP=100352.
// d_out = [ out (9,633,792 f32) | fmap (9,633,792 f32) ]
//
// ws layout (float index):
//   [   0, 4608) W1 bf16 A-frags: slot ((g*3+m)*3+k)*64+lane (16 B each),
//                w'[o=16m+(lane&15)][ci=32k+(lane>>4)*8+j], w' = w1*s1
//   [4608, 4800) c1[192] f32: c = b1/s1 (act' = max(x + c, 0))
//   [4800, 6336) W2 bf16 A-frags: slot ((G*2+m))*64+lane,
//                w2[o=G*32+16m+(lane&15)][ci=(lane>>4)*8+j]  (no fold)
//   [6336, 7104) p2[96][8]: c2=b2/s2, w00*s2, w01*s2, w10*s2, w11*s2,
//                ayax packed, off = ay*56+ax, pad
#define WSC_OFF 4608
#define WS_W2F  4800
#define WS_P    6336

#define HW 3136
#define CC 96
#define NB 32

typedef __attribute__((ext_vector_type(8))) short short8;
typedef __attribute__((ext_vector_type(4))) float float4_;

__global__ __launch_bounds__(128) void precompute_k(
    const float* __restrict__ g1, const float* __restrict__ be1,
    const float* __restrict__ m1, const float* __restrict__ v1,
    const float* __restrict__ g2, const float* __restrict__ be2,
    const float* __restrict__ m2, const float* __restrict__ v2,
    const float* __restrict__ w1, const float* __restrict__ w2,
    const float* __restrict__ shift, float* __restrict__ ws) {
  const int t = blockIdx.x * 128 + threadIdx.x;  // 12*128 = 1536 threads
  if (t < 192) {
    float s = g1[t] / sqrtf(v1[t] + 1e-5f);
    float b = be1[t] - m1[t] * s;
    ws[WSC_OFF + t] = b / s;     // gamma > 0 guaranteed
  }
  if (t >= 192 && t < 288) {     // conv2 per-channel params (s2 folded into w)
    int c = t - 192;
    float s = g2[c] / sqrtf(v2[c] + 1e-5f);
    float b = be2[c] - m2[c] * s;
    float dy = shift[2 * c], dx = shift[2 * c + 1];
    float fy = floorf(dy), fx = floorf(dx);
    float wy = dy - fy, wx = dx - fx;
    int ay = (int)fy, ax = (int)fx;
    float* pp = ws + WS_P + c * 8;
    pp[0] = b / s;                       // c2: q = s*relu(f + c2)
    pp[1] = (1.f - wy) * (1.f - wx) * s;
    pp[2] = (1.f - wy) * wx * s;
    pp[3] = wy * (1.f - wx) * s;
    pp[4] = wy * wx * s;
    pp[5] = __int_as_float((ay << 16) | (ax & 0xffff));
    pp[6] = __int_as_float(ay * 56 + ax);
    pp[7] = 0.f;
  }
  if (t < 1152) {                // W1 fragments (scale-folded bf16)
    const int lane = t & 63;
    const int gmk = t >> 6;      // 0..17
    const int k = gmk % 3;
    const int gm = gmk / 3;
    const int m = gm % 3;
    const int g = gm / 3;
    const int o = 16 * m + (lane & 15);
    const int ci0 = 32 * k + (lane >> 4) * 8;
    unsigned int pk[4];
    for (int jj = 0; jj < 4; ++jj) {
      unsigned short us[2];
      for (int h = 0; h < 2; ++h) {
        int ci = ci0 + 2 * jj + h;
        float s = g1[g * 96 + ci] / sqrtf(v1[g * 96 + ci] + 1e-5f);
        float w = w1[(g * 48 + o) * 96 + ci] * s;
        __hip_bfloat16 hb = __float2bfloat16(w);
        memcpy(&us[h], &hb, 2);
      }
      pk[jj] = (unsigned int)us[0] | ((unsigned int)us[1] << 16);
    }
    uint4 val;
    val.x = pk[0]; val.y = pk[1]; val.z = pk[2]; val.w = pk[3];
    ((uint4*)ws)[t] = val;
  } else if (t < 1536) {         // W2 fragments (plain bf16)
    const int s2i = t - 1152;    // 0..383
    const int lane = s2i & 63;
    const int gm = s2i >> 6;     // 0..5
    const int m = gm & 1;
    const int G = gm >> 1;
    const int o = G * 32 + m * 16 + (lane & 15);
    const int k0 = (lane >> 4) * 8;
    unsigned int pk[4];
    for (int jj = 0; jj < 4; ++jj) {
      unsigned short us[2];
      for (int h = 0; h < 2; ++h) {
        __hip_bfloat16 hb = __float2bfloat16(w2[o * 32 + k0 + 2 * jj + h]);
        memcpy(&us[h], &hb, 2);
      }
      pk[jj] = (unsigned int)us[0] | ((unsigned int)us[1] << 16);
    }
    uint4 val;
    val.x = pk[0]; val.y = pk[1]; val.z = pk[2]; val.w = pk[3];
    ((uint4*)(ws + WS_W2F))[s2i] = val;
  }
}

// ---------------------------------------------------------------------------
// K1 (MFMA): fmap = conv1x1_g2( bnrelu1( concat ), w1 )
// grid (784, 2) LINEAR — no XCD swizzle (A/B test: swizzled K1 = 43-45 us,
// r5's linear K1 = ~33 us). 784 % 8 == 0 => strip's XCD = strip % 8 for both
// groups, so K2 (same 128-px strips, linear) reads fmap from the local L2.
// Block 256 = 4 waves; wave = 2 tiles of 16 px.
// ---------------------------------------------------------------------------
__global__ __launch_bounds__(256) void k1_conv1(
    const float* __restrict__ x, const float* __restrict__ prev,
    const float* __restrict__ ws, float* __restrict__ fmap) {
  const int tid = threadIdx.x;
  const int lane = tid & 63;
  const int wv = tid >> 6;       // 0..3
  const int g = blockIdx.y;
  const int strip = blockIdx.x;  // linear
  const int q = lane >> 4;       // 0..3
  const int colL = lane & 15;

  short8 A[3][3];
  const short8* wf = (const short8*)ws;
#pragma unroll
  for (int m = 0; m < 3; ++m)
#pragma unroll
    for (int k = 0; k < 3; ++k)
      A[m][k] = wf[((g * 3 + m) * 3 + k) * 64 + lane];

  float c_[3][8];
#pragma unroll
  for (int k = 0; k < 3; ++k) {
    const float* cp = ws + WSC_OFF + g * 96 + 32 * k + 8 * q;
#pragma unroll
    for (int j = 0; j < 8; ++j) c_[k][j] = cp[j];
  }

  const int Pw = strip * 128 + wv * 32;   // 32 | 3136: n const per wave
  const int n = Pw / HW;
  const int pw = Pw - n * HW;
  const size_t nb = (size_t)n * CC * HW;

  // per-k source base (octets never straddle the x/prev split)
  const float* sb[3];
#pragma unroll
  for (int k = 0; k < 3; ++k) {
    const int ci0 = 32 * k + 8 * q;
    sb[k] = (ci0 < 48)
        ? (x + nb + (size_t)(g * 48 + ci0) * HW)
        : (prev + nb + (size_t)((1 - g) * 48 + (ci0 - 48)) * HW);
  }
  float* fb = fmap + nb + (size_t)(g * 48) * HW;

#pragma unroll
  for (int t = 0; t < 2; ++t) {
    const int col = pw + t * 16 + colL;
    float4_ D[3] = {{0.f, 0.f, 0.f, 0.f}, {0.f, 0.f, 0.f, 0.f},
                    {0.f, 0.f, 0.f, 0.f}};
#pragma unroll
    for (int k = 0; k < 3; ++k) {
      float a[8];
#pragma unroll
      for (int j = 0; j < 8; ++j) a[j] = sb[k][(size_t)j * HW + col];
      short8 B;
#pragma unroll
      for (int j = 0; j < 8; ++j) {
        float f = fmaxf(a[j] + c_[k][j], 0.f);
        __hip_bfloat16 hb = __float2bfloat16(f);
        unsigned short us;
        memcpy(&us, &hb, 2);
        B[j] = (short)us;
      }
#pragma unroll
      for (int m = 0; m < 3; ++m)
        D[m] = __builtin_amdgcn_mfma_f32_16x16x32_bf16(A[m][k], B, D[m],
                                                       0, 0, 0);
    }
#pragma unroll
    for (int m = 0; m < 3; ++m)
#pragma unroll
      for (int r = 0; r < 4; ++r)
        fb[(size_t)(16 * m + q * 4 + r) * HW + col] = D[m][r];
  }
}

// ---------------------------------------------------------------------------
// K2 (MFMA): out = conv1x1_g3( active_shift( bnrelu2(fmap) ), w2 ) + x
// grid (784, 3) LINEAR, 128-px strips matching K1 exactly (XCD = strip % 8
// for every group since 784 % 8 == 0) -> fmap producer/consumer share an L2.
// Block 256 = 4 waves; wave = 2 tiles of 16 px. 9408 waves.
// s2 folded into tap weights: h = sum w_tap*s2*relu(f_tap + c2).
// ---------------------------------------------------------------------------
__global__ __launch_bounds__(256) void k2_shift_conv2(
    const float* __restrict__ x, const float* __restrict__ fmap,
    const float* __restrict__ ws, float* __restrict__ out) {
  const int tid = threadIdx.x;
  const int G = blockIdx.y;        // group 0..2
  const int lane = tid & 63;
  const int wv = tid >> 6;         // 0..3
  const int q = lane >> 4;
  const int colL = lane & 15;
  const int strip = blockIdx.x;    // linear, same 128-px strips as K1

  short8 A0, A1;
  {
    const short8* wf2 = (const short8*)(ws + WS_W2F);
    A0 = wf2[(G * 2 + 0) * 64 + lane];
    A1 = wf2[(G * 2 + 1) * 64 + lane];
  }

  float c2_[8], w00_[8], w01_[8], w10_[8], w11_[8];
  int off_[8], ay_[8], ax_[8];
#pragma unroll
  for (int j = 0; j < 8; ++j) {
    const float* pp = ws + WS_P + (G * 32 + q * 8 + j) * 8;
    c2_[j] = pp[0];
    w00_[j] = pp[1];
    w01_[j] = pp[2];
    w10_[j] = pp[3];
    w11_[j] = pp[4];
    const int ayax = __float_as_int(pp[5]);
    ay_[j] = ayax >> 16;
    ax_[j] = (short)(ayax & 0xffff);
    off_[j] = __float_as_int(pp[6]);
  }

  const int Pw = strip * 128 + wv * 32;   // 32 | 3136: n const per wave
  const int n = Pw / HW;
  const int pw = Pw - n * HW;
  const int cb = n * CC + G * 32;
  const float* fb = fmap + (size_t)cb * HW;
  const float* xb = x + (size_t)cb * HW;
  float* ob = out + (size_t)cb * HW;

#pragma unroll
  for (int t = 0; t < 2; ++t) {
    const int p = pw + t * 16 + colL;
    const int y = p / 56;
    const int xx = p - y * 56;

    // residual prefetch (independent of gather chain)
    float xr0[4], xr1[4];
#pragma unroll
    for (int r = 0; r < 4; ++r) {
      xr0[r] = xb[(size_t)(q * 4 + r) * HW + p];
      xr1[r] = xb[(size_t)(16 + q * 4 + r) * HW + p];
    }

    short8 B;
#pragma unroll
    for (int j = 0; j < 8; ++j) {
      const int ci = q * 8 + j;
      const float* fc = fb + (size_t)ci * HW;
      const int to = p + off_[j];
      float f00 = fc[to];
      float f01 = fc[min(to + 1, HW - 1)];
      float f10 = fc[min(to + 56, HW - 1)];
      float f11 = fc[min(to + 57, HW - 1)];
      float q00 = fmaxf(f00 + c2_[j], 0.f);
      float q01 = fmaxf(f01 + c2_[j], 0.f);
      float q10 = fmaxf(f10 + c2_[j], 0.f);
      float q11 = fmaxf(f11 + c2_[j], 0.f);
      const int yq = y + ay_[j], xq = xx + ax_[j];
      const bool vy0 = yq >= 0, vy1 = yq <= 54;
      const bool vx0 = xq >= 0, vx1 = xq <= 54;
      float h = ((vy0 && vx0) ? w00_[j] : 0.f) * q00;
      h = fmaf(((vy0 && vx1) ? w01_[j] : 0.f), q01, h);
      h = fmaf(((vy1 && vx0) ? w10_[j] : 0.f), q10, h);
      h = fmaf(((vy1 && vx1) ? w11_[j] : 0.f), q11, h);
      __hip_bfloat16 hb = __float2bfloat16(h);
      unsigned short us;
      memcpy(&us, &hb, 2);
      B[j] = (short)us;
    }

    float4_ D0 = {0.f, 0.f, 0.f, 0.f};
    float4_ D1 = {0.f, 0.f, 0.f, 0.f};
    D0 = __builtin_amdgcn_mfma_f32_16x16x32_bf16(A0, B, D0, 0, 0, 0);
    D1 = __builtin_amdgcn_mfma_f32_16x16x32_bf16(A1, B, D1, 0, 0, 0);

#pragma unroll
    for (int r = 0; r < 4; ++r) {
      ob[(size_t)(q * 4 + r) * HW + p] = D0[r] + xr0[r];
      ob[(size_t)(16 + q * 4 + r) * HW + p] = D1[r] + xr1[r];
    }
  }
}

extern "C" void kernel_launch(void* const* d_in, const int* in_sizes, int n_in,
                              void* d_out, int out_size, void* d_ws, size_t ws_size,
                              hipStream_t stream) {
  const float* x     = (const float*)d_in[0];
  const float* prev  = (const float*)d_in[1];
  const float* g1    = (const float*)d_in[2];
  const float* be1   = (const float*)d_in[3];
  const float* m1    = (const float*)d_in[4];
  const float* v1    = (const float*)d_in[5];
  const float* g2    = (const float*)d_in[6];
  const float* be2   = (const float*)d_in[7];
  const float* m2    = (const float*)d_in[8];
  const float* v2    = (const float*)d_in[9];
  const float* w1    = (const float*)d_in[10];
  const float* w2    = (const float*)d_in[11];
  const float* shift = (const float*)d_in[12];

  float* out  = (float*)d_out;
  float* fmap = out + (size_t)NB * CC * HW;  // second output, written in place
  float* ws   = (float*)d_ws;

  precompute_k<<<12, 128, 0, stream>>>(g1, be1, m1, v1, g2, be2, m2, v2,
                                       w1, w2, shift, ws);
  k1_conv1<<<dim3(784, 2), 256, 0, stream>>>(x, prev, ws, fmap);
  k2_shift_conv2<<<dim3(784, 3), 256, 0, stream>>>(x, fmap, ws, out);
}